// Round 1
// baseline (464.190 us; speedup 1.0000x reference)
//
#include <hip/hip_runtime.h>
#include <hip/hip_bf16.h>
#include <cstdint>
#include <cstddef>

typedef unsigned short ushort_t;
typedef __bf16 bf16x8 __attribute__((ext_vector_type(8)));
typedef float f32x4 __attribute__((ext_vector_type(4)));

#define D_MODEL 1024
#define D_FF 4096
#define BB 2
#define SS 2048
#define NH 16
#define MROWS (BB * SS) /* 4096 */

__device__ __forceinline__ ushort_t f2bf(float f) {
  union { float f; unsigned u; } x; x.f = f;
  unsigned r = x.u + 0x7fffu + ((x.u >> 16) & 1u);
  return (ushort_t)(r >> 16);
}

__device__ __forceinline__ void gload_lds16(const void* g, void* l) {
  __builtin_amdgcn_global_load_lds((const __attribute__((address_space(1))) void*)g,
                                   (__attribute__((address_space(3))) void*)l, 16, 0, 0);
}

// ---------------- LayerNorm (fp32 in -> bf16 out) ----------------
__global__ __launch_bounds__(256) void ln_bf16_kernel(
    const float* __restrict__ x, const float* __restrict__ w,
    const float* __restrict__ b, ushort_t* __restrict__ out) {
  int row = blockIdx.x;
  int tid = threadIdx.x;
  int lane = tid & 63, wid = tid >> 6;
  const float4 v = ((const float4*)(x + (size_t)row * D_MODEL))[tid];
  float s = v.x + v.y + v.z + v.w;
  __shared__ float red[8];
  #pragma unroll
  for (int o = 32; o > 0; o >>= 1) s += __shfl_down(s, o);
  if (lane == 0) red[wid] = s;
  __syncthreads();
  float mu = (red[0] + red[1] + red[2] + red[3]) * (1.0f / D_MODEL);
  float d0 = v.x - mu, d1 = v.y - mu, d2 = v.z - mu, d3 = v.w - mu;
  float sq = d0 * d0 + d1 * d1 + d2 * d2 + d3 * d3;
  #pragma unroll
  for (int o = 32; o > 0; o >>= 1) sq += __shfl_down(sq, o);
  if (lane == 0) red[4 + wid] = sq;
  __syncthreads();
  float var = (red[4] + red[5] + red[6] + red[7]) * (1.0f / D_MODEL);
  float rstd = rsqrtf(var + 1e-5f);
  const float4 wv = ((const float4*)w)[tid];
  const float4 bv = ((const float4*)b)[tid];
  ushort4 o4;
  o4.x = f2bf(d0 * rstd * wv.x + bv.x);
  o4.y = f2bf(d1 * rstd * wv.y + bv.y);
  o4.z = f2bf(d2 * rstd * wv.z + bv.z);
  o4.w = f2bf(d3 * rstd * wv.w + bv.w);
  ((ushort4*)(out + (size_t)row * D_MODEL))[tid] = o4;
}

// ---------------- transpose + cast: W[K][N] fp32 -> Wt[N][K] bf16 ----------------
__global__ __launch_bounds__(256) void transpose_cast_kernel(
    const float* __restrict__ W, ushort_t* __restrict__ Wt, int K, int N) {
  __shared__ float tile[32][33];
  int bx = blockIdx.x * 32;  // n
  int by = blockIdx.y * 32;  // k
  int tx = threadIdx.x, ty = threadIdx.y;  // 32 x 8
  #pragma unroll
  for (int i = 0; i < 32; i += 8)
    tile[ty + i][tx] = W[(size_t)(by + ty + i) * N + bx + tx];
  __syncthreads();
  #pragma unroll
  for (int i = 0; i < 32; i += 8)
    Wt[(size_t)(bx + ty + i) * K + by + tx] = f2bf(tile[tx][ty + i]);
}

// ---------------- GEMM: C[M][N] = A[M][K](bf16) @ Bt[N][K]^T(bf16) + bias (+resid)(relu) ----------------
template <bool RELU, bool RESID, bool OUTBF>
__global__ __launch_bounds__(256) void gemm_bt_kernel(
    const ushort_t* __restrict__ A, const ushort_t* __restrict__ Bt,
    const float* __restrict__ bias, const float* __restrict__ resid,
    void* __restrict__ Cout, int M, int N, int K) {
  __shared__ __align__(16) ushort_t lA[128 * 32];
  __shared__ __align__(16) ushort_t lB[128 * 32];
  const int tid = threadIdx.x, lane = tid & 63, wid = tid >> 6;
  const int row0 = blockIdx.y * 128, col0 = blockIdx.x * 128;
  const int wr = (wid >> 1) * 64, wc = (wid & 1) * 64;
  f32x4 acc[4][4] = {};
  const int eBase = wid * 512 + lane * 8;
  for (int k0 = 0; k0 < K; k0 += 32) {
    __syncthreads();
    #pragma unroll
    for (int i = 0; i < 2; i++) {
      int e = i * 2048 + eBase;
      int r = e >> 5, kk = e & 31;
      gload_lds16(A + (size_t)(row0 + r) * K + k0 + kk, lA + i * 2048 + wid * 512);
      gload_lds16(Bt + (size_t)(col0 + r) * K + k0 + kk, lB + i * 2048 + wid * 512);
    }
    __syncthreads();
    bf16x8 af[4], bfr[4];
    #pragma unroll
    for (int mi = 0; mi < 4; mi++)
      af[mi] = *(const bf16x8*)(lA + (wr + mi * 16 + (lane & 15)) * 32 + (lane >> 4) * 8);
    #pragma unroll
    for (int ni = 0; ni < 4; ni++)
      bfr[ni] = *(const bf16x8*)(lB + (wc + ni * 16 + (lane & 15)) * 32 + (lane >> 4) * 8);
    #pragma unroll
    for (int mi = 0; mi < 4; mi++)
      #pragma unroll
      for (int ni = 0; ni < 4; ni++)
        acc[mi][ni] = __builtin_amdgcn_mfma_f32_16x16x32_bf16(af[mi], bfr[ni], acc[mi][ni], 0, 0, 0);
  }
  #pragma unroll
  for (int ni = 0; ni < 4; ni++) {
    int col = col0 + wc + ni * 16 + (lane & 15);
    float bv = bias[col];
    #pragma unroll
    for (int mi = 0; mi < 4; mi++) {
      #pragma unroll
      for (int r = 0; r < 4; r++) {
        int row = row0 + wr + mi * 16 + (lane >> 4) * 4 + r;
        float v = acc[mi][ni][r] + bv;
        if (RESID) v += resid[(size_t)row * N + col];
        if (RELU) v = fmaxf(v, 0.0f);
        if (OUTBF) ((ushort_t*)Cout)[(size_t)row * N + col] = f2bf(v);
        else ((float*)Cout)[(size_t)row * N + col] = v;
      }
    }
  }
}

// ---------------- flash attention: qkv[4096][3072] bf16 -> ctx[4096][1024] bf16 ----------------
__global__ __launch_bounds__(256) void attn_kernel(
    const ushort_t* __restrict__ qkv, ushort_t* __restrict__ ctx) {
  __shared__ __align__(16) ushort_t Vt[64 * 32];       // [d][key_local]
  __shared__ __align__(16) ushort_t Plds[4][16 * 32];  // per-wave [q_local][key_local]
  const int tid = threadIdx.x, lane = tid & 63, wid = tid >> 6;
  const int b = blockIdx.y >> 4, h = blockIdx.y & 15;
  const int q0 = blockIdx.x * 64 + wid * 16;
  const ushort_t* base = qkv + (size_t)b * SS * 3072 + h * 64;
  const ushort_t* Qp = base;
  const ushort_t* Kp = base + 1024;
  const ushort_t* Vp = base + 2048;

  bf16x8 qf[2];
  {
    int qr = q0 + (lane & 15);
    #pragma unroll
    for (int s2 = 0; s2 < 2; s2++)
      qf[s2] = *(const bf16x8*)(Qp + (size_t)qr * 3072 + s2 * 32 + (lane >> 4) * 8);
  }
  float m[4], l[4];
  f32x4 acc[4] = {};
  #pragma unroll
  for (int r = 0; r < 4; r++) { m[r] = -1e30f; l[r] = 0.f; }

  for (int kv = 0; kv < SS; kv += 32) {
    __syncthreads();
    {
      int key = tid >> 3, dd = (tid & 7) * 8;
      bf16x8 vv = *(const bf16x8*)(Vp + (size_t)(kv + key) * 3072 + dd);
      union { bf16x8 v; ushort_t u[8]; } cv; cv.v = vv;
      #pragma unroll
      for (int j = 0; j < 8; j++) Vt[(dd + j) * 32 + key] = cv.u[j];
    }
    __syncthreads();
    f32x4 s[2] = {};
    #pragma unroll
    for (int g = 0; g < 2; g++) {
      int key = kv + g * 16 + (lane & 15);
      #pragma unroll
      for (int s2 = 0; s2 < 2; s2++) {
        bf16x8 kf = *(const bf16x8*)(Kp + (size_t)key * 3072 + s2 * 32 + (lane >> 4) * 8);
        s[g] = __builtin_amdgcn_mfma_f32_16x16x32_bf16(qf[s2], kf, s[g], 0, 0, 0);
      }
    }
    #pragma unroll
    for (int g = 0; g < 2; g++)
      #pragma unroll
      for (int r = 0; r < 4; r++) s[g][r] *= 0.125f;  // 1/sqrt(64)
    #pragma unroll
    for (int r = 0; r < 4; r++) {
      float mt = fmaxf(s[0][r], s[1][r]);
      #pragma unroll
      for (int o = 1; o < 16; o <<= 1) mt = fmaxf(mt, __shfl_xor(mt, o));
      float mn = fmaxf(m[r], mt);
      float alpha = __expf(m[r] - mn);
      m[r] = mn;
      float p0 = __expf(s[0][r] - mn);
      float p1 = __expf(s[1][r] - mn);
      s[0][r] = p0; s[1][r] = p1;
      float ps = p0 + p1;
      #pragma unroll
      for (int o = 1; o < 16; o <<= 1) ps += __shfl_xor(ps, o);
      l[r] = l[r] * alpha + ps;
      #pragma unroll
      for (int f = 0; f < 4; f++) acc[f][r] *= alpha;
    }
    #pragma unroll
    for (int g = 0; g < 2; g++)
      #pragma unroll
      for (int r = 0; r < 4; r++)
        Plds[wid][((lane >> 4) * 4 + r) * 32 + g * 16 + (lane & 15)] = f2bf(s[g][r]);
    asm volatile("s_waitcnt lgkmcnt(0)" ::: "memory");
    __builtin_amdgcn_sched_barrier(0);
    bf16x8 pf = *(const bf16x8*)(&Plds[wid][(lane & 15) * 32 + (lane >> 4) * 8]);
    #pragma unroll
    for (int f = 0; f < 4; f++) {
      bf16x8 vf = *(const bf16x8*)(Vt + (f * 16 + (lane & 15)) * 32 + (lane >> 4) * 8);
      acc[f] = __builtin_amdgcn_mfma_f32_16x16x32_bf16(pf, vf, acc[f], 0, 0, 0);
    }
  }
  #pragma unroll
  for (int f = 0; f < 4; f++)
    #pragma unroll
    for (int r = 0; r < 4; r++) {
      int row = b * SS + q0 + (lane >> 4) * 4 + r;
      int col = h * 64 + f * 16 + (lane & 15);
      ctx[(size_t)row * D_MODEL + col] = f2bf(acc[f][r] / l[r]);
    }
}

extern "C" void kernel_launch(void* const* d_in, const int* in_sizes, int n_in,
                              void* d_out, int out_size, void* d_ws, size_t ws_size,
                              hipStream_t stream) {
  const float* x    = (const float*)d_in[0];
  const float* ln1w = (const float*)d_in[1];
  const float* ln1b = (const float*)d_in[2];
  const float* Wq   = (const float*)d_in[3];
  const float* bq   = (const float*)d_in[4];
  const float* Wk   = (const float*)d_in[5];
  const float* bk   = (const float*)d_in[6];
  const float* Wv   = (const float*)d_in[7];
  const float* bv   = (const float*)d_in[8];
  const float* Wo   = (const float*)d_in[9];
  const float* bo   = (const float*)d_in[10];
  const float* ln2w = (const float*)d_in[11];
  const float* ln2b = (const float*)d_in[12];
  const float* W1   = (const float*)d_in[13];
  const float* b1   = (const float*)d_in[14];
  const float* W2   = (const float*)d_in[15];
  const float* b2   = (const float*)d_in[16];

  char* ws = (char*)d_ws;
  size_t off = 0;
  auto alloc = [&](size_t bytes) {
    void* p = ws + off;
    off += (bytes + 255) & ~(size_t)255;
    return p;
  };
  ushort_t* Wt_qkv = (ushort_t*)alloc((size_t)3072 * 1024 * 2);
  ushort_t* Wt_o   = (ushort_t*)alloc((size_t)1024 * 1024 * 2);
  ushort_t* Wt_1   = (ushort_t*)alloc((size_t)4096 * 1024 * 2);
  ushort_t* Wt_2   = (ushort_t*)alloc((size_t)1024 * 4096 * 2);
  float*    bqkv   = (float*)alloc((size_t)3072 * 4);
  ushort_t* qkvb   = (ushort_t*)alloc((size_t)MROWS * 3072 * 2);  // 24 MB
  ushort_t* ctxb   = (ushort_t*)alloc((size_t)MROWS * 1024 * 2);  // 8 MB, contiguous after qkvb
  ushort_t* hbuf   = (ushort_t*)alloc((size_t)MROWS * 1024 * 2);
  float*    x2     = (float*)alloc((size_t)MROWS * 1024 * 4);
  ushort_t* ff1    = qkvb;  // reuse qkv(24MB)+ctx(8MB) = 32MB for [4096][4096] bf16
  float*    outp   = (float*)d_out;

  dim3 tb(32, 8);
  transpose_cast_kernel<<<dim3(32, 32), tb, 0, stream>>>(Wq, Wt_qkv, 1024, 1024);
  transpose_cast_kernel<<<dim3(32, 32), tb, 0, stream>>>(Wk, Wt_qkv + 1024 * 1024, 1024, 1024);
  transpose_cast_kernel<<<dim3(32, 32), tb, 0, stream>>>(Wv, Wt_qkv + 2 * 1024 * 1024, 1024, 1024);
  transpose_cast_kernel<<<dim3(32, 32), tb, 0, stream>>>(Wo, Wt_o, 1024, 1024);
  transpose_cast_kernel<<<dim3(128, 32), tb, 0, stream>>>(W1, Wt_1, 1024, 4096);
  transpose_cast_kernel<<<dim3(32, 128), tb, 0, stream>>>(W2, Wt_2, 4096, 1024);
  hipMemcpyAsync(bqkv,        bq, 1024 * 4, hipMemcpyDeviceToDevice, stream);
  hipMemcpyAsync(bqkv + 1024, bk, 1024 * 4, hipMemcpyDeviceToDevice, stream);
  hipMemcpyAsync(bqkv + 2048, bv, 1024 * 4, hipMemcpyDeviceToDevice, stream);

  // LN1 -> h
  ln_bf16_kernel<<<MROWS, 256, 0, stream>>>(x, ln1w, ln1b, hbuf);
  // fused QKV GEMM: [4096,1024]x[1024,3072]
  gemm_bt_kernel<false, false, true><<<dim3(3072 / 128, MROWS / 128), 256, 0, stream>>>(
      hbuf, Wt_qkv, bqkv, nullptr, qkvb, MROWS, 3072, 1024);
  // attention
  attn_kernel<<<dim3(SS / 64, BB * NH), 256, 0, stream>>>(qkvb, ctxb);
  // O-proj + residual(x) -> x2 (fp32)
  gemm_bt_kernel<false, true, false><<<dim3(1024 / 128, MROWS / 128), 256, 0, stream>>>(
      ctxb, Wt_o, bo, x, x2, MROWS, 1024, 1024);
  // LN2 -> h
  ln_bf16_kernel<<<MROWS, 256, 0, stream>>>(x2, ln2w, ln2b, hbuf);
  // FFN1 + relu -> ff1 (bf16)
  gemm_bt_kernel<true, false, true><<<dim3(D_FF / 128, MROWS / 128), 256, 0, stream>>>(
      hbuf, Wt_1, b1, nullptr, ff1, MROWS, D_FF, 1024);
  // FFN2 + residual(x2) -> out (fp32)
  gemm_bt_kernel<false, true, false><<<dim3(1024 / 128, MROWS / 128), 256, 0, stream>>>(
      ff1, Wt_2, b2, x2, outp, MROWS, 1024, D_FF);
}

// Round 2
// 392.612 us; speedup vs baseline: 1.1823x; 1.1823x over previous
//
#include <hip/hip_runtime.h>
#include <hip/hip_bf16.h>
#include <cstdint>
#include <cstddef>

typedef unsigned short ushort_t;
typedef __bf16 bf16x8 __attribute__((ext_vector_type(8)));
typedef float f32x4 __attribute__((ext_vector_type(4)));

#define D_MODEL 1024
#define D_FF 4096
#define BB 2
#define SS 2048
#define NH 16
#define MROWS (BB * SS) /* 4096 */
#define KVBLK 64

__device__ __forceinline__ ushort_t f2bf(float f) {
  union { float f; unsigned u; } x; x.f = f;
  unsigned r = x.u + 0x7fffu + ((x.u >> 16) & 1u);
  return (ushort_t)(r >> 16);
}

__device__ __forceinline__ void gload_lds16(const void* g, void* l) {
  __builtin_amdgcn_global_load_lds((const __attribute__((address_space(1))) void*)g,
                                   (__attribute__((address_space(3))) void*)l, 16, 0, 0);
}

// 16-lane butterfly reductions on the VALU via DPP (no LDS traffic)
__device__ __forceinline__ float dpp_max16(float x) {
  int v;
  v = __builtin_amdgcn_update_dpp(0, __float_as_int(x), 0xB1, 0xF, 0xF, true);  // quad_perm(1,0,3,2)
  x = fmaxf(x, __int_as_float(v));
  v = __builtin_amdgcn_update_dpp(0, __float_as_int(x), 0x4E, 0xF, 0xF, true);  // quad_perm(2,3,0,1)
  x = fmaxf(x, __int_as_float(v));
  v = __builtin_amdgcn_update_dpp(0, __float_as_int(x), 0x141, 0xF, 0xF, true); // row_half_mirror
  x = fmaxf(x, __int_as_float(v));
  v = __builtin_amdgcn_update_dpp(0, __float_as_int(x), 0x140, 0xF, 0xF, true); // row_mirror
  x = fmaxf(x, __int_as_float(v));
  return x;
}
__device__ __forceinline__ float dpp_sum16(float x) {
  int v;
  v = __builtin_amdgcn_update_dpp(0, __float_as_int(x), 0xB1, 0xF, 0xF, true);
  x += __int_as_float(v);
  v = __builtin_amdgcn_update_dpp(0, __float_as_int(x), 0x4E, 0xF, 0xF, true);
  x += __int_as_float(v);
  v = __builtin_amdgcn_update_dpp(0, __float_as_int(x), 0x141, 0xF, 0xF, true);
  x += __int_as_float(v);
  v = __builtin_amdgcn_update_dpp(0, __float_as_int(x), 0x140, 0xF, 0xF, true);
  x += __int_as_float(v);
  return x;
}

// ---------------- LayerNorm (fp32 in -> bf16 out) ----------------
__global__ __launch_bounds__(256) void ln_bf16_kernel(
    const float* __restrict__ x, const float* __restrict__ w,
    const float* __restrict__ b, ushort_t* __restrict__ out) {
  int row = blockIdx.x;
  int tid = threadIdx.x;
  int lane = tid & 63, wid = tid >> 6;
  const float4 v = ((const float4*)(x + (size_t)row * D_MODEL))[tid];
  float s = v.x + v.y + v.z + v.w;
  __shared__ float red[8];
  #pragma unroll
  for (int o = 32; o > 0; o >>= 1) s += __shfl_down(s, o);
  if (lane == 0) red[wid] = s;
  __syncthreads();
  float mu = (red[0] + red[1] + red[2] + red[3]) * (1.0f / D_MODEL);
  float d0 = v.x - mu, d1 = v.y - mu, d2 = v.z - mu, d3 = v.w - mu;
  float sq = d0 * d0 + d1 * d1 + d2 * d2 + d3 * d3;
  #pragma unroll
  for (int o = 32; o > 0; o >>= 1) sq += __shfl_down(sq, o);
  if (lane == 0) red[4 + wid] = sq;
  __syncthreads();
  float var = (red[4] + red[5] + red[6] + red[7]) * (1.0f / D_MODEL);
  float rstd = rsqrtf(var + 1e-5f);
  const float4 wv = ((const float4*)w)[tid];
  const float4 bv = ((const float4*)b)[tid];
  ushort4 o4;
  o4.x = f2bf(d0 * rstd * wv.x + bv.x);
  o4.y = f2bf(d1 * rstd * wv.y + bv.y);
  o4.z = f2bf(d2 * rstd * wv.z + bv.z);
  o4.w = f2bf(d3 * rstd * wv.w + bv.w);
  ((ushort4*)(out + (size_t)row * D_MODEL))[tid] = o4;
}

// ---------------- transpose + cast: W[K][N] fp32 -> Wt[N][K] bf16 ----------------
__global__ __launch_bounds__(256) void transpose_cast_kernel(
    const float* __restrict__ W, ushort_t* __restrict__ Wt, int K, int N) {
  __shared__ float tile[32][33];
  int bx = blockIdx.x * 32;  // n
  int by = blockIdx.y * 32;  // k
  int tx = threadIdx.x, ty = threadIdx.y;  // 32 x 8
  #pragma unroll
  for (int i = 0; i < 32; i += 8)
    tile[ty + i][tx] = W[(size_t)(by + ty + i) * N + bx + tx];
  __syncthreads();
  #pragma unroll
  for (int i = 0; i < 32; i += 8)
    Wt[(size_t)(bx + ty + i) * K + by + tx] = f2bf(tile[tx][ty + i]);
}

// ---------------- V transpose: qkv V-slice -> Vt[bh][64 d][SS keys] bf16 ----------------
__global__ __launch_bounds__(256) void vtrans_kernel(
    const ushort_t* __restrict__ qkv, ushort_t* __restrict__ Vt) {
  __shared__ __align__(16) ushort_t T[64 * 64];  // [key][d], chunk-XOR swizzled
  const int tid = threadIdx.x;
  const int bh = blockIdx.y, b = bh >> 4, h = bh & 15;
  const int kv0 = blockIdx.x * 64;
  const ushort_t* Vp = qkv + (size_t)b * SS * 3072 + 2048 + h * 64;
  #pragma unroll
  for (int i = 0; i < 2; i++) {
    int idx = tid * 2 + i;          // chunk index
    int key = idx >> 3, c = idx & 7;
    bf16x8 v = *(const bf16x8*)(Vp + (size_t)(kv0 + key) * 3072 + c * 8);
    *(bf16x8*)(T + key * 64 + ((c ^ (key & 7)) * 8)) = v;
  }
  __syncthreads();
  int d = tid >> 2, kb = tid & 3;
  ushort_t o[16];
  #pragma unroll
  for (int j = 0; j < 16; j++) {
    int key = kb * 16 + j;
    o[j] = T[key * 64 + (((d >> 3) ^ (key & 7)) * 8) + (d & 7)];
  }
  ushort_t* dst = Vt + (size_t)(bh * 64 + d) * SS + kv0 + kb * 16;
  *(bf16x8*)dst = *(bf16x8*)&o[0];
  *(bf16x8*)(dst + 8) = *(bf16x8*)&o[8];
}

// ---------------- GEMM: C[M][N] = A[M][K](bf16) @ Bt[N][K]^T(bf16) + bias (+resid)(relu) ----------------
template <bool RELU, bool RESID, bool OUTBF>
__global__ __launch_bounds__(256) void gemm_bt_kernel(
    const ushort_t* __restrict__ A, const ushort_t* __restrict__ Bt,
    const float* __restrict__ bias, const float* __restrict__ resid,
    void* __restrict__ Cout, int M, int N, int K) {
  __shared__ __align__(16) ushort_t lA[128 * 32];
  __shared__ __align__(16) ushort_t lB[128 * 32];
  const int tid = threadIdx.x, lane = tid & 63, wid = tid >> 6;
  // XCD-aware bijective swizzle (all grids are multiples of 8)
  const int gx = gridDim.x;
  int bid = blockIdx.y * gx + blockIdx.x;
  int nwg = gx * gridDim.y;
  int w = (bid & 7) * (nwg >> 3) + (bid >> 3);
  const int row0 = (w / gx) * 128, col0 = (w % gx) * 128;
  const int wr = (wid >> 1) * 64, wc = (wid & 1) * 64;
  f32x4 acc[4][4] = {};
  const int eBase = wid * 512 + lane * 8;
  for (int k0 = 0; k0 < K; k0 += 32) {
    __syncthreads();
    #pragma unroll
    for (int i = 0; i < 2; i++) {
      int e = i * 2048 + eBase;
      int r = e >> 5, kk = e & 31;
      gload_lds16(A + (size_t)(row0 + r) * K + k0 + kk, lA + i * 2048 + wid * 512);
      gload_lds16(Bt + (size_t)(col0 + r) * K + k0 + kk, lB + i * 2048 + wid * 512);
    }
    __syncthreads();
    bf16x8 af[4], bfr[4];
    #pragma unroll
    for (int mi = 0; mi < 4; mi++)
      af[mi] = *(const bf16x8*)(lA + (wr + mi * 16 + (lane & 15)) * 32 + (lane >> 4) * 8);
    #pragma unroll
    for (int ni = 0; ni < 4; ni++)
      bfr[ni] = *(const bf16x8*)(lB + (wc + ni * 16 + (lane & 15)) * 32 + (lane >> 4) * 8);
    #pragma unroll
    for (int mi = 0; mi < 4; mi++)
      #pragma unroll
      for (int ni = 0; ni < 4; ni++)
        acc[mi][ni] = __builtin_amdgcn_mfma_f32_16x16x32_bf16(af[mi], bfr[ni], acc[mi][ni], 0, 0, 0);
  }
  #pragma unroll
  for (int ni = 0; ni < 4; ni++) {
    int col = col0 + wc + ni * 16 + (lane & 15);
    float bv = bias[col];
    #pragma unroll
    for (int mi = 0; mi < 4; mi++) {
      #pragma unroll
      for (int r = 0; r < 4; r++) {
        int row = row0 + wr + mi * 16 + (lane >> 4) * 4 + r;
        float v = acc[mi][ni][r] + bv;
        if (RESID) v += resid[(size_t)row * N + col];
        if (RELU) v = fmaxf(v, 0.0f);
        if (OUTBF) ((ushort_t*)Cout)[(size_t)row * N + col] = f2bf(v);
        else ((float*)Cout)[(size_t)row * N + col] = v;
      }
    }
  }
}

// ---------------- flash attention ----------------
// qkv[4096][3072] bf16 (Q|K|V), Vt[bh][64][2048] bf16 -> ctx[4096][1024] bf16
__global__ __launch_bounds__(256) void attn_kernel(
    const ushort_t* __restrict__ qkv, const ushort_t* __restrict__ Vt,
    ushort_t* __restrict__ ctx) {
  __shared__ __align__(16) ushort_t Vl[2][64 * 64];   // [d][key] swizzled, 8KB each
  __shared__ __align__(16) ushort_t Pl[4][16 * 72];   // per-wave P, row stride 72
  const int tid = threadIdx.x, lane = tid & 63, wid = tid >> 6;
  // XCD swizzle: co-locate same-head q-tiles on one XCD (grid 32x32 = 1024 wgs)
  int bid = blockIdx.y * 32 + blockIdx.x;
  int w = (bid & 7) * 128 + (bid >> 3);
  const int bh = w >> 5, qt = w & 31;
  const int b = bh >> 4, h = bh & 15;
  const int q0 = qt * 64 + wid * 16;
  const ushort_t* Qp = qkv + (size_t)b * SS * 3072 + h * 64;
  const ushort_t* Kp = Qp + 1024;
  const ushort_t* Vg = Vt + (size_t)bh * 64 * SS;

  bf16x8 qf[2];
  {
    int qr = q0 + (lane & 15);
    #pragma unroll
    for (int s2 = 0; s2 < 2; s2++)
      qf[s2] = *(const bf16x8*)(Qp + (size_t)qr * 3072 + s2 * 32 + (lane >> 4) * 8);
  }
  float m[4], l[4];
  f32x4 acc[4] = {};
  #pragma unroll
  for (int r = 0; r < 4; r++) { m[r] = -1e30f; l[r] = 0.f; }

  // stage V tile t into buffer buf (pre-swizzled source -> linear LDS)
  auto stageV = [&](int buf, int t) {
    int kv = t * KVBLK;
    #pragma unroll
    for (int i = 0; i < 2; i++) {
      int idx = wid * 128 + i * 64 + lane;  // 16B-chunk index
      int d = idx >> 3, c = idx & 7;
      gload_lds16(Vg + (size_t)d * SS + kv + ((c ^ (d & 7)) * 8),
                  &Vl[buf][wid * 1024 + i * 512]);
    }
  };

  stageV(0, 0);
  int cur = 0;
  const int NT = SS / KVBLK;
  for (int t = 0; t < NT; ++t) {
    __syncthreads();  // drains vmcnt: Vl[cur] ready; prev compute done
    if (t + 1 < NT) stageV(cur ^ 1, t + 1);
    const int kv = t * KVBLK;

    // QK^T: S[16q][64k]
    f32x4 s[4] = {};
    #pragma unroll
    for (int g = 0; g < 4; g++) {
      int key = kv + g * 16 + (lane & 15);
      #pragma unroll
      for (int s2 = 0; s2 < 2; s2++) {
        bf16x8 kf = *(const bf16x8*)(Kp + (size_t)key * 3072 + s2 * 32 + (lane >> 4) * 8);
        s[g] = __builtin_amdgcn_mfma_f32_16x16x32_bf16(qf[s2], kf, s[g], 0, 0, 0);
      }
    }
    // online softmax (per q-row r), DPP reductions on the VALU
    #pragma unroll
    for (int r = 0; r < 4; r++) {
      float mt = fmaxf(fmaxf(s[0][r] , s[1][r]), fmaxf(s[2][r], s[3][r])) * 0.125f;
      mt = dpp_max16(mt);
      float mn = fmaxf(m[r], mt);
      float alpha = __expf(m[r] - mn);
      m[r] = mn;
      float ps = 0.f;
      int qrow = (lane >> 4) * 4 + r;
      #pragma unroll
      for (int g = 0; g < 4; g++) {
        float p = __expf(s[g][r] * 0.125f - mn);
        ps += p;
        Pl[wid][qrow * 72 + g * 16 + (lane & 15)] = f2bf(p);
      }
      ps = dpp_sum16(ps);
      l[r] = l[r] * alpha + ps;
      #pragma unroll
      for (int f = 0; f < 4; f++) acc[f][r] *= alpha;
    }
    asm volatile("s_waitcnt lgkmcnt(0)" ::: "memory");
    __builtin_amdgcn_sched_barrier(0);
    // PV: A = P[16q][64k], B = V^T tiles from LDS
    bf16x8 pf[2];
    #pragma unroll
    for (int ks = 0; ks < 2; ks++)
      pf[ks] = *(const bf16x8*)(&Pl[wid][(lane & 15) * 72 + ks * 32 + (lane >> 4) * 8]);
    #pragma unroll
    for (int f = 0; f < 4; f++) {
      int d = f * 16 + (lane & 15);
      #pragma unroll
      for (int ks = 0; ks < 2; ks++) {
        int chunk = (ks * 4 + (lane >> 4)) ^ (d & 7);
        bf16x8 vf = *(const bf16x8*)(&Vl[cur][d * 64 + chunk * 8]);
        acc[f] = __builtin_amdgcn_mfma_f32_16x16x32_bf16(pf[ks], vf, acc[f], 0, 0, 0);
      }
    }
    cur ^= 1;
  }
  #pragma unroll
  for (int f = 0; f < 4; f++)
    #pragma unroll
    for (int r = 0; r < 4; r++) {
      int row = b * SS + q0 + (lane >> 4) * 4 + r;
      int col = h * 64 + f * 16 + (lane & 15);
      ctx[(size_t)row * D_MODEL + col] = f2bf(acc[f][r] / l[r]);
    }
}

extern "C" void kernel_launch(void* const* d_in, const int* in_sizes, int n_in,
                              void* d_out, int out_size, void* d_ws, size_t ws_size,
                              hipStream_t stream) {
  const float* x    = (const float*)d_in[0];
  const float* ln1w = (const float*)d_in[1];
  const float* ln1b = (const float*)d_in[2];
  const float* Wq   = (const float*)d_in[3];
  const float* bq   = (const float*)d_in[4];
  const float* Wk   = (const float*)d_in[5];
  const float* bk   = (const float*)d_in[6];
  const float* Wv   = (const float*)d_in[7];
  const float* bv   = (const float*)d_in[8];
  const float* Wo   = (const float*)d_in[9];
  const float* bo   = (const float*)d_in[10];
  const float* ln2w = (const float*)d_in[11];
  const float* ln2b = (const float*)d_in[12];
  const float* W1   = (const float*)d_in[13];
  const float* b1   = (const float*)d_in[14];
  const float* W2   = (const float*)d_in[15];
  const float* b2   = (const float*)d_in[16];

  char* ws = (char*)d_ws;
  size_t off = 0;
  auto alloc = [&](size_t bytes) {
    void* p = ws + off;
    off += (bytes + 255) & ~(size_t)255;
    return p;
  };
  ushort_t* Wt_qkv = (ushort_t*)alloc((size_t)3072 * 1024 * 2);
  ushort_t* Wt_o   = (ushort_t*)alloc((size_t)1024 * 1024 * 2);
  ushort_t* Wt_1   = (ushort_t*)alloc((size_t)4096 * 1024 * 2);
  ushort_t* Wt_2   = (ushort_t*)alloc((size_t)1024 * 4096 * 2);
  float*    bqkv   = (float*)alloc((size_t)3072 * 4);
  ushort_t* qkvb   = (ushort_t*)alloc((size_t)MROWS * 3072 * 2);  // 24 MB
  ushort_t* ctxb   = (ushort_t*)alloc((size_t)MROWS * 1024 * 2);  // 8 MB
  ushort_t* hbuf   = (ushort_t*)alloc((size_t)MROWS * 1024 * 2);
  float*    x2     = (float*)alloc((size_t)MROWS * 1024 * 4);
  ushort_t* Vtb    = (ushort_t*)alloc((size_t)BB * NH * 64 * SS * 2);  // 8 MB
  ushort_t* ff1    = qkvb;  // reuse qkv(24MB)+ctx(8MB) = 32MB for [4096][4096] bf16
  float*    outp   = (float*)d_out;

  dim3 tb(32, 8);
  transpose_cast_kernel<<<dim3(32, 32), tb, 0, stream>>>(Wq, Wt_qkv, 1024, 1024);
  transpose_cast_kernel<<<dim3(32, 32), tb, 0, stream>>>(Wk, Wt_qkv + 1024 * 1024, 1024, 1024);
  transpose_cast_kernel<<<dim3(32, 32), tb, 0, stream>>>(Wv, Wt_qkv + 2 * 1024 * 1024, 1024, 1024);
  transpose_cast_kernel<<<dim3(32, 32), tb, 0, stream>>>(Wo, Wt_o, 1024, 1024);
  transpose_cast_kernel<<<dim3(128, 32), tb, 0, stream>>>(W1, Wt_1, 1024, 4096);
  transpose_cast_kernel<<<dim3(32, 128), tb, 0, stream>>>(W2, Wt_2, 4096, 1024);
  hipMemcpyAsync(bqkv,        bq, 1024 * 4, hipMemcpyDeviceToDevice, stream);
  hipMemcpyAsync(bqkv + 1024, bk, 1024 * 4, hipMemcpyDeviceToDevice, stream);
  hipMemcpyAsync(bqkv + 2048, bv, 1024 * 4, hipMemcpyDeviceToDevice, stream);

  // LN1 -> h
  ln_bf16_kernel<<<MROWS, 256, 0, stream>>>(x, ln1w, ln1b, hbuf);
  // fused QKV GEMM: [4096,1024]x[1024,3072]
  gemm_bt_kernel<false, false, true><<<dim3(3072 / 128, MROWS / 128), 256, 0, stream>>>(
      hbuf, Wt_qkv, bqkv, nullptr, qkvb, MROWS, 3072, 1024);
  // V transpose -> Vt[bh][64][2048]
  vtrans_kernel<<<dim3(SS / 64, BB * NH), 256, 0, stream>>>(qkvb, Vtb);
  // attention
  attn_kernel<<<dim3(SS / 64, BB * NH), 256, 0, stream>>>(qkvb, Vtb, ctxb);
  // O-proj + residual(x) -> x2 (fp32)
  gemm_bt_kernel<false, true, false><<<dim3(1024 / 128, MROWS / 128), 256, 0, stream>>>(
      ctxb, Wt_o, bo, x, x2, MROWS, 1024, 1024);
  // LN2 -> h
  ln_bf16_kernel<<<MROWS, 256, 0, stream>>>(x2, ln2w, ln2b, hbuf);
  // FFN1 + relu -> ff1 (bf16)
  gemm_bt_kernel<true, false, true><<<dim3(D_FF / 128, MROWS / 128), 256, 0, stream>>>(
      hbuf, Wt_1, b1, nullptr, ff1, MROWS, D_FF, 1024);
  // FFN2 + residual(x2) -> out (fp32)
  gemm_bt_kernel<false, true, false><<<dim3(1024 / 128, MROWS / 128), 256, 0, stream>>>(
      ff1, Wt_2, b2, x2, outp, MROWS, 1024, D_FF);
}

// Round 3
// 388.974 us; speedup vs baseline: 1.1934x; 1.0094x over previous
//
#include <hip/hip_runtime.h>
#include <hip/hip_bf16.h>
#include <cstdint>
#include <cstddef>

typedef unsigned short ushort_t;
typedef __bf16 bf16x8 __attribute__((ext_vector_type(8)));
typedef float f32x4 __attribute__((ext_vector_type(4)));

#define D_MODEL 1024
#define D_FF 4096
#define BB 2
#define SS 2048
#define NH 16
#define MROWS (BB * SS) /* 4096 */
#define KVBLK 64

__device__ __forceinline__ ushort_t f2bf(float f) {
  union { float f; unsigned u; } x; x.f = f;
  unsigned r = x.u + 0x7fffu + ((x.u >> 16) & 1u);
  return (ushort_t)(r >> 16);
}

__device__ __forceinline__ void gload_lds16(const void* g, void* l) {
  __builtin_amdgcn_global_load_lds((const __attribute__((address_space(1))) void*)g,
                                   (__attribute__((address_space(3))) void*)l, 16, 0, 0);
}

// 16-lane butterfly reductions on the VALU via DPP (no LDS traffic)
__device__ __forceinline__ float dpp_max16(float x) {
  int v;
  v = __builtin_amdgcn_update_dpp(0, __float_as_int(x), 0xB1, 0xF, 0xF, true);  // quad_perm(1,0,3,2)
  x = fmaxf(x, __int_as_float(v));
  v = __builtin_amdgcn_update_dpp(0, __float_as_int(x), 0x4E, 0xF, 0xF, true);  // quad_perm(2,3,0,1)
  x = fmaxf(x, __int_as_float(v));
  v = __builtin_amdgcn_update_dpp(0, __float_as_int(x), 0x141, 0xF, 0xF, true); // row_half_mirror
  x = fmaxf(x, __int_as_float(v));
  v = __builtin_amdgcn_update_dpp(0, __float_as_int(x), 0x140, 0xF, 0xF, true); // row_mirror
  x = fmaxf(x, __int_as_float(v));
  return x;
}
__device__ __forceinline__ float dpp_sum16(float x) {
  int v;
  v = __builtin_amdgcn_update_dpp(0, __float_as_int(x), 0xB1, 0xF, 0xF, true);
  x += __int_as_float(v);
  v = __builtin_amdgcn_update_dpp(0, __float_as_int(x), 0x4E, 0xF, 0xF, true);
  x += __int_as_float(v);
  v = __builtin_amdgcn_update_dpp(0, __float_as_int(x), 0x141, 0xF, 0xF, true);
  x += __int_as_float(v);
  v = __builtin_amdgcn_update_dpp(0, __float_as_int(x), 0x140, 0xF, 0xF, true);
  x += __int_as_float(v);
  return x;
}

// ---------------- LayerNorm (fp32 in -> bf16 out) ----------------
__global__ __launch_bounds__(256) void ln_bf16_kernel(
    const float* __restrict__ x, const float* __restrict__ w,
    const float* __restrict__ b, ushort_t* __restrict__ out) {
  int row = blockIdx.x;
  int tid = threadIdx.x;
  int lane = tid & 63, wid = tid >> 6;
  const float4 v = ((const float4*)(x + (size_t)row * D_MODEL))[tid];
  float s = v.x + v.y + v.z + v.w;
  __shared__ float red[8];
  #pragma unroll
  for (int o = 32; o > 0; o >>= 1) s += __shfl_down(s, o);
  if (lane == 0) red[wid] = s;
  __syncthreads();
  float mu = (red[0] + red[1] + red[2] + red[3]) * (1.0f / D_MODEL);
  float d0 = v.x - mu, d1 = v.y - mu, d2 = v.z - mu, d3 = v.w - mu;
  float sq = d0 * d0 + d1 * d1 + d2 * d2 + d3 * d3;
  #pragma unroll
  for (int o = 32; o > 0; o >>= 1) sq += __shfl_down(sq, o);
  if (lane == 0) red[4 + wid] = sq;
  __syncthreads();
  float var = (red[4] + red[5] + red[6] + red[7]) * (1.0f / D_MODEL);
  float rstd = rsqrtf(var + 1e-5f);
  const float4 wv = ((const float4*)w)[tid];
  const float4 bv = ((const float4*)b)[tid];
  ushort4 o4;
  o4.x = f2bf(d0 * rstd * wv.x + bv.x);
  o4.y = f2bf(d1 * rstd * wv.y + bv.y);
  o4.z = f2bf(d2 * rstd * wv.z + bv.z);
  o4.w = f2bf(d3 * rstd * wv.w + bv.w);
  ((ushort4*)(out + (size_t)row * D_MODEL))[tid] = o4;
}

// ---------------- transpose + cast: W[K][N] fp32 -> Wt[N][K] bf16 ----------------
__global__ __launch_bounds__(256) void transpose_cast_kernel(
    const float* __restrict__ W, ushort_t* __restrict__ Wt, int K, int N) {
  __shared__ float tile[32][33];
  int bx = blockIdx.x * 32;  // n
  int by = blockIdx.y * 32;  // k
  int tx = threadIdx.x, ty = threadIdx.y;  // 32 x 8
  #pragma unroll
  for (int i = 0; i < 32; i += 8)
    tile[ty + i][tx] = W[(size_t)(by + ty + i) * N + bx + tx];
  __syncthreads();
  #pragma unroll
  for (int i = 0; i < 32; i += 8)
    Wt[(size_t)(bx + ty + i) * K + by + tx] = f2bf(tile[tx][ty + i]);
}

// ---------------- V transpose: qkv V-slice -> Vt[bh][64 d][SS keys] bf16 ----------------
__global__ __launch_bounds__(256) void vtrans_kernel(
    const ushort_t* __restrict__ qkv, ushort_t* __restrict__ Vt) {
  __shared__ __align__(16) ushort_t T[64 * 64];  // [key][d], chunk-XOR swizzled
  const int tid = threadIdx.x;
  const int bh = blockIdx.y, b = bh >> 4, h = bh & 15;
  const int kv0 = blockIdx.x * 64;
  const ushort_t* Vp = qkv + (size_t)b * SS * 3072 + 2048 + h * 64;
  #pragma unroll
  for (int i = 0; i < 2; i++) {
    int idx = tid * 2 + i;          // chunk index
    int key = idx >> 3, c = idx & 7;
    bf16x8 v = *(const bf16x8*)(Vp + (size_t)(kv0 + key) * 3072 + c * 8);
    *(bf16x8*)(T + key * 64 + ((c ^ (key & 7)) * 8)) = v;
  }
  __syncthreads();
  int d = tid >> 2, kb = tid & 3;
  ushort_t o[16];
  #pragma unroll
  for (int j = 0; j < 16; j++) {
    int key = kb * 16 + j;
    o[j] = T[key * 64 + (((d >> 3) ^ (key & 7)) * 8) + (d & 7)];
  }
  ushort_t* dst = Vt + (size_t)(bh * 64 + d) * SS + kv0 + kb * 16;
  *(bf16x8*)dst = *(bf16x8*)&o[0];
  *(bf16x8*)(dst + 8) = *(bf16x8*)&o[8];
}

// ---------------- GEMM: C[M][N] = A[M][K](bf16) @ Bt[N][K]^T(bf16) + bias (+resid)(relu) ----------------
template <bool RELU, bool RESID, bool OUTBF>
__global__ __launch_bounds__(256) void gemm_bt_kernel(
    const ushort_t* __restrict__ A, const ushort_t* __restrict__ Bt,
    const float* __restrict__ bias, const float* __restrict__ resid,
    void* __restrict__ Cout, int M, int N, int K) {
  __shared__ __align__(16) ushort_t lA[128 * 32];
  __shared__ __align__(16) ushort_t lB[128 * 32];
  const int tid = threadIdx.x, lane = tid & 63, wid = tid >> 6;
  // XCD-aware bijective swizzle (all grids are multiples of 8)
  const int gx = gridDim.x;
  int bid = blockIdx.y * gx + blockIdx.x;
  int nwg = gx * gridDim.y;
  int w = (bid & 7) * (nwg >> 3) + (bid >> 3);
  const int row0 = (w / gx) * 128, col0 = (w % gx) * 128;
  const int wr = (wid >> 1) * 64, wc = (wid & 1) * 64;
  f32x4 acc[4][4] = {};
  const int eBase = wid * 512 + lane * 8;
  for (int k0 = 0; k0 < K; k0 += 32) {
    __syncthreads();
    #pragma unroll
    for (int i = 0; i < 2; i++) {
      int e = i * 2048 + eBase;
      int r = e >> 5, kk = e & 31;
      gload_lds16(A + (size_t)(row0 + r) * K + k0 + kk, lA + i * 2048 + wid * 512);
      gload_lds16(Bt + (size_t)(col0 + r) * K + k0 + kk, lB + i * 2048 + wid * 512);
    }
    __syncthreads();
    bf16x8 af[4], bfr[4];
    #pragma unroll
    for (int mi = 0; mi < 4; mi++)
      af[mi] = *(const bf16x8*)(lA + (wr + mi * 16 + (lane & 15)) * 32 + (lane >> 4) * 8);
    #pragma unroll
    for (int ni = 0; ni < 4; ni++)
      bfr[ni] = *(const bf16x8*)(lB + (wc + ni * 16 + (lane & 15)) * 32 + (lane >> 4) * 8);
    #pragma unroll
    for (int mi = 0; mi < 4; mi++)
      #pragma unroll
      for (int ni = 0; ni < 4; ni++)
        acc[mi][ni] = __builtin_amdgcn_mfma_f32_16x16x32_bf16(af[mi], bfr[ni], acc[mi][ni], 0, 0, 0);
  }
  #pragma unroll
  for (int ni = 0; ni < 4; ni++) {
    int col = col0 + wc + ni * 16 + (lane & 15);
    float bv = bias[col];
    #pragma unroll
    for (int mi = 0; mi < 4; mi++) {
      #pragma unroll
      for (int r = 0; r < 4; r++) {
        int row = row0 + wr + mi * 16 + (lane >> 4) * 4 + r;
        float v = acc[mi][ni][r] + bv;
        if (RESID) v += resid[(size_t)row * N + col];
        if (RELU) v = fmaxf(v, 0.0f);
        if (OUTBF) ((ushort_t*)Cout)[(size_t)row * N + col] = f2bf(v);
        else ((float*)Cout)[(size_t)row * N + col] = v;
      }
    }
  }
}

// ---------------- flash attention ----------------
// qkv[4096][3072] bf16 (Q|K|V), Vt[bh][64][2048] bf16 -> ctx[4096][1024] bf16
__global__ __launch_bounds__(256) void attn_kernel(
    const ushort_t* __restrict__ qkv, const ushort_t* __restrict__ Vt,
    ushort_t* __restrict__ ctx) {
  __shared__ __align__(16) ushort_t Vl[2][64 * 64];   // [d][key] swizzled, 8KB each
  __shared__ __align__(16) ushort_t Pl[4][16 * 72];   // per-wave P, row stride 72
  const int tid = threadIdx.x, lane = tid & 63, wid = tid >> 6;
  // XCD swizzle: co-locate same-head q-tiles on one XCD (grid 32x32 = 1024 wgs)
  int bid = blockIdx.y * 32 + blockIdx.x;
  int w = (bid & 7) * 128 + (bid >> 3);
  const int bh = w >> 5, qt = w & 31;
  const int b = bh >> 4, h = bh & 15;
  const int q0 = qt * 64 + wid * 16;
  const ushort_t* Qp = qkv + (size_t)b * SS * 3072 + h * 64;
  const ushort_t* Kp = Qp + 1024;
  const ushort_t* Vg = Vt + (size_t)bh * 64 * SS;

  bf16x8 qf[2];
  {
    int qr = q0 + (lane & 15);
    #pragma unroll
    for (int s2 = 0; s2 < 2; s2++)
      qf[s2] = *(const bf16x8*)(Qp + (size_t)qr * 3072 + s2 * 32 + (lane >> 4) * 8);
  }
  float m[4], l[4];
  f32x4 acc[4] = {};
  #pragma unroll
  for (int r = 0; r < 4; r++) { m[r] = -1e30f; l[r] = 0.f; }

  // stage V tile t into buffer buf (pre-swizzled source -> linear LDS)
  auto stageV = [&](int buf, int t) {
    int kv = t * KVBLK;
    #pragma unroll
    for (int i = 0; i < 2; i++) {
      int idx = wid * 128 + i * 64 + lane;  // 16B-chunk index
      int d = idx >> 3, c = idx & 7;
      gload_lds16(Vg + (size_t)d * SS + kv + ((c ^ (d & 7)) * 8),
                  &Vl[buf][wid * 1024 + i * 512]);
    }
  };

  stageV(0, 0);
  int cur = 0;
  const int NT = SS / KVBLK;
  const float Cs = 0.18033688011f;  // 0.125 * log2(e)
  for (int t = 0; t < NT; ++t) {
    __syncthreads();  // drains vmcnt: Vl[cur] ready; prev compute done
    if (t + 1 < NT) stageV(cur ^ 1, t + 1);
    const int kv = t * KVBLK;

    // QK^T: group g covers keys kv + (lane&15)*4 + g  (lane's 4 g-values = 4 consecutive keys)
    f32x4 s4[4] = {};
    const ushort_t* kbase = Kp + (size_t)(kv + (lane & 15) * 4) * 3072 + (lane >> 4) * 8;
    #pragma unroll
    for (int g = 0; g < 4; g++) {
      bf16x8 kf0 = *(const bf16x8*)(kbase + (size_t)g * 3072);
      bf16x8 kf1 = *(const bf16x8*)(kbase + (size_t)g * 3072 + 32);
      s4[g] = __builtin_amdgcn_mfma_f32_16x16x32_bf16(qf[0], kf0, s4[g], 0, 0, 0);
      s4[g] = __builtin_amdgcn_mfma_f32_16x16x32_bf16(qf[1], kf1, s4[g], 0, 0, 0);
    }
    // online softmax in exp2 domain (m,l in s*Cs units); defer-max THR=8
    float mt[4];
    #pragma unroll
    for (int r = 0; r < 4; r++) {
      float a = fmaxf(fmaxf(s4[0][r], s4[1][r]), fmaxf(s4[2][r], s4[3][r]));
      mt[r] = dpp_max16(a) * Cs;
    }
    bool need = false;
    #pragma unroll
    for (int r = 0; r < 4; r++) need |= (mt[r] > m[r] + 8.0f);
    if (__any(need)) {
      #pragma unroll
      for (int r = 0; r < 4; r++) {
        float mn = fmaxf(m[r], mt[r]);
        float al = __builtin_amdgcn_exp2f(m[r] - mn);
        m[r] = mn;
        l[r] *= al;
        #pragma unroll
        for (int f = 0; f < 4; f++) acc[f][r] *= al;
      }
    }
    const int qrow = (lane >> 4) * 4;
    #pragma unroll
    for (int r = 0; r < 4; r++) {
      float nm = -m[r];
      float p0 = __builtin_amdgcn_exp2f(fmaf(s4[0][r], Cs, nm));
      float p1 = __builtin_amdgcn_exp2f(fmaf(s4[1][r], Cs, nm));
      float p2 = __builtin_amdgcn_exp2f(fmaf(s4[2][r], Cs, nm));
      float p3 = __builtin_amdgcn_exp2f(fmaf(s4[3][r], Cs, nm));
      l[r] += (p0 + p1) + (p2 + p3);
      unsigned w0, w1;
      asm("v_cvt_pk_bf16_f32 %0, %1, %2" : "=v"(w0) : "v"(p0), "v"(p1));
      asm("v_cvt_pk_bf16_f32 %0, %1, %2" : "=v"(w1) : "v"(p2), "v"(p3));
      uint2 pw; pw.x = w0; pw.y = w1;
      *(uint2*)(&Pl[wid][(qrow + r) * 72 + (lane & 15) * 4]) = pw;
    }
    asm volatile("s_waitcnt lgkmcnt(0)" ::: "memory");
    __builtin_amdgcn_sched_barrier(0);
    // PV: A = P[16q][64k], B = V^T tiles from LDS
    bf16x8 pf[2];
    #pragma unroll
    for (int ks = 0; ks < 2; ks++)
      pf[ks] = *(const bf16x8*)(&Pl[wid][(lane & 15) * 72 + ks * 32 + (lane >> 4) * 8]);
    #pragma unroll
    for (int f = 0; f < 4; f++) {
      int d = f * 16 + (lane & 15);
      #pragma unroll
      for (int ks = 0; ks < 2; ks++) {
        int chunk = (ks * 4 + (lane >> 4)) ^ (d & 7);
        bf16x8 vf = *(const bf16x8*)(&Vl[cur][d * 64 + chunk * 8]);
        acc[f] = __builtin_amdgcn_mfma_f32_16x16x32_bf16(pf[ks], vf, acc[f], 0, 0, 0);
      }
    }
    cur ^= 1;
  }
  #pragma unroll
  for (int r = 0; r < 4; r++) l[r] = dpp_sum16(l[r]);
  float rl[4];
  #pragma unroll
  for (int r = 0; r < 4; r++) rl[r] = 1.0f / l[r];
  #pragma unroll
  for (int f = 0; f < 4; f++)
    #pragma unroll
    for (int r = 0; r < 4; r++) {
      int row = b * SS + q0 + (lane >> 4) * 4 + r;
      int col = h * 64 + f * 16 + (lane & 15);
      ctx[(size_t)row * D_MODEL + col] = f2bf(acc[f][r] * rl[r]);
    }
}

extern "C" void kernel_launch(void* const* d_in, const int* in_sizes, int n_in,
                              void* d_out, int out_size, void* d_ws, size_t ws_size,
                              hipStream_t stream) {
  const float* x    = (const float*)d_in[0];
  const float* ln1w = (const float*)d_in[1];
  const float* ln1b = (const float*)d_in[2];
  const float* Wq   = (const float*)d_in[3];
  const float* bq   = (const float*)d_in[4];
  const float* Wk   = (const float*)d_in[5];
  const float* bk   = (const float*)d_in[6];
  const float* Wv   = (const float*)d_in[7];
  const float* bv   = (const float*)d_in[8];
  const float* Wo   = (const float*)d_in[9];
  const float* bo   = (const float*)d_in[10];
  const float* ln2w = (const float*)d_in[11];
  const float* ln2b = (const float*)d_in[12];
  const float* W1   = (const float*)d_in[13];
  const float* b1   = (const float*)d_in[14];
  const float* W2   = (const float*)d_in[15];
  const float* b2   = (const float*)d_in[16];

  char* ws = (char*)d_ws;
  size_t off = 0;
  auto alloc = [&](size_t bytes) {
    void* p = ws + off;
    off += (bytes + 255) & ~(size_t)255;
    return p;
  };
  ushort_t* Wt_qkv = (ushort_t*)alloc((size_t)3072 * 1024 * 2);
  ushort_t* Wt_o   = (ushort_t*)alloc((size_t)1024 * 1024 * 2);
  ushort_t* Wt_1   = (ushort_t*)alloc((size_t)4096 * 1024 * 2);
  ushort_t* Wt_2   = (ushort_t*)alloc((size_t)1024 * 4096 * 2);
  float*    bqkv   = (float*)alloc((size_t)3072 * 4);
  ushort_t* qkvb   = (ushort_t*)alloc((size_t)MROWS * 3072 * 2);  // 24 MB
  ushort_t* ctxb   = (ushort_t*)alloc((size_t)MROWS * 1024 * 2);  // 8 MB
  ushort_t* hbuf   = (ushort_t*)alloc((size_t)MROWS * 1024 * 2);
  float*    x2     = (float*)alloc((size_t)MROWS * 1024 * 4);
  ushort_t* Vtb    = (ushort_t*)alloc((size_t)BB * NH * 64 * SS * 2);  // 8 MB
  ushort_t* ff1    = qkvb;  // reuse qkv(24MB)+ctx(8MB) = 32MB for [4096][4096] bf16
  float*    outp   = (float*)d_out;

  dim3 tb(32, 8);
  transpose_cast_kernel<<<dim3(32, 32), tb, 0, stream>>>(Wq, Wt_qkv, 1024, 1024);
  transpose_cast_kernel<<<dim3(32, 32), tb, 0, stream>>>(Wk, Wt_qkv + 1024 * 1024, 1024, 1024);
  transpose_cast_kernel<<<dim3(32, 32), tb, 0, stream>>>(Wv, Wt_qkv + 2 * 1024 * 1024, 1024, 1024);
  transpose_cast_kernel<<<dim3(32, 32), tb, 0, stream>>>(Wo, Wt_o, 1024, 1024);
  transpose_cast_kernel<<<dim3(128, 32), tb, 0, stream>>>(W1, Wt_1, 1024, 4096);
  transpose_cast_kernel<<<dim3(32, 128), tb, 0, stream>>>(W2, Wt_2, 4096, 1024);
  hipMemcpyAsync(bqkv,        bq, 1024 * 4, hipMemcpyDeviceToDevice, stream);
  hipMemcpyAsync(bqkv + 1024, bk, 1024 * 4, hipMemcpyDeviceToDevice, stream);
  hipMemcpyAsync(bqkv + 2048, bv, 1024 * 4, hipMemcpyDeviceToDevice, stream);

  // LN1 -> h
  ln_bf16_kernel<<<MROWS, 256, 0, stream>>>(x, ln1w, ln1b, hbuf);
  // fused QKV GEMM: [4096,1024]x[1024,3072]
  gemm_bt_kernel<false, false, true><<<dim3(3072 / 128, MROWS / 128), 256, 0, stream>>>(
      hbuf, Wt_qkv, bqkv, nullptr, qkvb, MROWS, 3072, 1024);
  // V transpose -> Vt[bh][64][2048]
  vtrans_kernel<<<dim3(SS / 64, BB * NH), 256, 0, stream>>>(qkvb, Vtb);
  // attention
  attn_kernel<<<dim3(SS / 64, BB * NH), 256, 0, stream>>>(qkvb, Vtb, ctxb);
  // O-proj + residual(x) -> x2 (fp32)
  gemm_bt_kernel<false, true, false><<<dim3(1024 / 128, MROWS / 128), 256, 0, stream>>>(
      ctxb, Wt_o, bo, x, x2, MROWS, 1024, 1024);
  // LN2 -> h
  ln_bf16_kernel<<<MROWS, 256, 0, stream>>>(x2, ln2w, ln2b, hbuf);
  // FFN1 + relu -> ff1 (bf16)
  gemm_bt_kernel<true, false, true><<<dim3(D_FF / 128, MROWS / 128), 256, 0, stream>>>(
      hbuf, Wt_1, b1, nullptr, ff1, MROWS, D_FF, 1024);
  // FFN2 + residual(x2) -> out (fp32)
  gemm_bt_kernel<false, true, false><<<dim3(1024 / 128, MROWS / 128), 256, 0, stream>>>(
      ff1, Wt_2, b2, x2, outp, MROWS, 1024, D_FF);
}